// Round 1
// baseline (100.529 us; speedup 1.0000x reference)
//
#include <hip/hip_runtime.h>

// MaxSel: max over 4 directional 3x3 Laplacians, zero-padded, 48x 512x512 fp32 images.
// Memory-bound stencil: each thread computes a 4-row x 4-col output patch using a
// 3-row register window over 6 input rows (1 float4 + 2 scalar halo loads per row).

#define HH 512
#define WW 512
#define IMG (HH * WW)

struct Row {
    float c[4];  // aligned quad
    float l, r;  // halo: w-1 and w+4
};

__device__ __forceinline__ float getv(const Row& rw, int j) {
    // j in [-1, 4]; resolved at compile time under full unroll
    if (j < 0) return rw.l;
    if (j > 3) return rw.r;
    return rw.c[j];
}

__global__ __launch_bounds__(256) void lapmax_kernel(const float* __restrict__ x,
                                                     float* __restrict__ out) {
    const int tid = blockIdx.x * 256 + threadIdx.x;
    const int wq  = tid & 127;          // 128 quads of 4 columns
    const int rg  = (tid >> 7) & 127;   // 128 row-groups of 4 rows
    const int img = tid >> 14;          // 48 images

    const int w  = wq << 2;
    const int h0 = rg << 2;

    const float* base  = x   + (size_t)img * IMG;
    float*       obase = out + (size_t)img * IMG;

    Row rows[3];

#pragma unroll
    for (int k = 0; k < 6; ++k) {
        const int r = h0 - 1 + k;
        Row& rw = rows[k % 3];
        if (r >= 0 && r < HH) {
            const float* p = base + r * WW + w;
            const float4 v = *reinterpret_cast<const float4*>(p);
            rw.c[0] = v.x; rw.c[1] = v.y; rw.c[2] = v.z; rw.c[3] = v.w;
            rw.l = (w > 0)       ? p[-1] : 0.0f;
            rw.r = (w < WW - 4)  ? p[4]  : 0.0f;
        } else {
            rw.c[0] = rw.c[1] = rw.c[2] = rw.c[3] = 0.0f;
            rw.l = 0.0f; rw.r = 0.0f;
        }

        if (k >= 2) {
            const Row& up  = rows[(k - 2) % 3];
            const Row& mid = rows[(k - 1) % 3];
            const Row& dn  = rows[k % 3];
            float o[4];
#pragma unroll
            for (int j = 0; j < 4; ++j) {
                const float sh  = getv(mid, j - 1) + getv(mid, j + 1); // horizontal
                const float sv  = getv(up,  j)     + getv(dn,  j);     // vertical
                const float sd1 = getv(up,  j + 1) + getv(dn,  j - 1); // anti-diag
                const float sd2 = getv(up,  j - 1) + getv(dn,  j + 1); // main diag
                const float m = fmaxf(fmaxf(sh, sv), fmaxf(sd1, sd2));
                o[j] = fmaf(-2.0f, mid.c[j], m);
            }
            const int orow = h0 + k - 2;
            *reinterpret_cast<float4*>(obase + (size_t)orow * WW + w) =
                make_float4(o[0], o[1], o[2], o[3]);
        }
    }
}

extern "C" void kernel_launch(void* const* d_in, const int* in_sizes, int n_in,
                              void* d_out, int out_size, void* d_ws, size_t ws_size,
                              hipStream_t stream) {
    const float* x = (const float*)d_in[0];
    float* out = (float*)d_out;

    // total elements = nimg * 512 * 512; each thread covers 16 outputs (4x4 patch)
    const int total    = in_sizes[0];
    const int nthreads = total / 16;
    const int blocks   = (nthreads + 255) / 256;

    lapmax_kernel<<<blocks, 256, 0, stream>>>(x, out);
}